// Round 13
// baseline (265.915 us; speedup 1.0000x reference)
//
#include <hip/hip_runtime.h>
#include <stdint.h>

#define N_NODES 100000
#define N_EDGES 1600000
#define NFEAT 256
#define NHID 64
#define N_ELEMS (N_NODES * NHID)   // 6,400,000

// Slotted row-buckets of 128 rows.
#define BSHIFT 7
#define NBUCK 782                  // ceil(100000/128)
#define CHUNK 2048                 // edges per bucket block
#define NBBLK ((N_EDGES + CHUNK - 1) / CHUNK)   // 782
#define CAP 2560                   // records staged/sorted; mean 2048 +11sigma
#define SLOTSZ 4096                // slot stride (records) = 32KB = agg rows of bucket

// R21: 512-thread fused blocks, 1:1 interleave (odd = bucket).
#define GB_TOTAL 1564              // 782 gemm (128 rows each) + 782 bucket
#define GB_LDS 34816               // max(gemm Bt 33.8KB, bucket 32KB) -> 4 blocks/CU

// Config (validated R6/R7): inputs f32, output f32, dropout = JAX partitionable
// threefry (key=(0,42), counter (0,i), bits = o0^o1).
//
// R20 post-mortem: occupancy 24->33% but gemm_bucket 68->75us -- halved CHUNK
//   doubled per-block fixed costs (1024-counter zero/scan/reserve x782) and
//   WRITE 32->38MB (2.6-rec runs). Gain and loss cancelled; total -2.5us.
// R21: occupancy via BIGGER BLOCKS, not smaller LDS. 512-thread blocks:
//   gemm = 128 rows/block, 8 waves share one 33.8KB Bt -> at 34KB alloc,
//   4 blocks/CU x 8 waves = 32 waves/CU ceiling (2x R20); W-convert halves.
//   bucket = CHUNK 2048 at 4 edges/thread, same 782 blocks (overhead flat).
//   __launch_bounds__(512,8) pins VGPR<=64 (measured 28) for the ceiling.
// Pipeline: memset -> gemm_bucket -> placegather -> apply.
//
// ws layout:
//   sums[128] f32 | bcnt[1024] i32 | agg[NBUCK*SLOTSZ*8 B = 25.62MB]
// support[6.4M] bf16 staged in d_out (dead before apply overwrites).
// bucketed aliases agg with per-bucket 32KB slots (SLOTSZ records).

typedef __attribute__((ext_vector_type(8))) short bf16x8;
typedef __attribute__((ext_vector_type(4))) float f32x4;

__device__ __forceinline__ unsigned short f2bf(float f) {
    uint32_t u = __float_as_uint(f);
    u += 0x7FFFu + ((u >> 16) & 1u);   // RNE
    return (unsigned short)(u >> 16);
}
__device__ __forceinline__ float bf2f(unsigned short u) {
    return __uint_as_float(((uint32_t)u) << 16);
}

// ---------------------------------------------------------------------------
// Fused GEMM | Bucket (R21). 512 threads. Role by blockIdx parity:
// even -> gemm block (gemm_id = bid>>1, 128 rows), odd -> bucket block
// (bblk = bid>>1, 2048 edges). Dynamic LDS 34KB, per-role layout.
// ---------------------------------------------------------------------------
__global__ __launch_bounds__(512, 8) void gemm_bucket_kernel(const float* __restrict__ x,
                                                             const float* __restrict__ W,
                                                             unsigned short* __restrict__ support,
                                                             const int* __restrict__ row,
                                                             const int* __restrict__ col,
                                                             const float* __restrict__ ew,
                                                             int* __restrict__ bcnt,
                                                             int2* __restrict__ bucketed) {
    extern __shared__ char smem[];
    const int t = threadIdx.x;
    const int bid = blockIdx.x;

    if ((bid & 1) == 0) {
        // ---------------- GEMM role: 128 rows ----------------
        const int gemm_id = bid >> 1;
        const int row0 = gemm_id * 128;
        if (row0 >= N_NODES) return;

        unsigned short (*Bt)[264] = (unsigned short (*)[264])smem;  // 33.8 KB

        #pragma unroll
        for (int i = 0; i < 32; i++) {
            int idx = i * 512 + t;
            Bt[idx & 63][idx >> 6] = f2bf(W[idx]);
        }
        __syncthreads();

        const int lane = t & 63;
        const int w = t >> 6;              // 0..7
        const int m = lane & 15;
        const int q = lane >> 4;
        const int growA = row0 + w * 16 + m;
        const int lrow = (growA < N_NODES) ? growA : N_NODES - 1;
        const float* xr = x + (size_t)lrow * NFEAT;

        f32x4 acc0 = {0.f, 0.f, 0.f, 0.f};
        f32x4 acc1 = acc0, acc2 = acc0, acc3 = acc0;

        #pragma unroll
        for (int ks = 0; ks < NFEAT; ks += 32) {
            float4 xa = *(const float4*)&xr[ks + q * 8];
            float4 xb = *(const float4*)&xr[ks + q * 8 + 4];
            ushort4 ua, ub;
            ua.x = f2bf(xa.x); ua.y = f2bf(xa.y); ua.z = f2bf(xa.z); ua.w = f2bf(xa.w);
            ub.x = f2bf(xb.x); ub.y = f2bf(xb.y); ub.z = f2bf(xb.z); ub.w = f2bf(xb.w);
            union { ushort4 u4[2]; bf16x8 v8; } cv;
            cv.u4[0] = ua; cv.u4[1] = ub;
            bf16x8 af = cv.v8;

            bf16x8 b0 = *(const bf16x8*)&Bt[ 0 + m][ks + q * 8];
            bf16x8 b1 = *(const bf16x8*)&Bt[16 + m][ks + q * 8];
            bf16x8 b2 = *(const bf16x8*)&Bt[32 + m][ks + q * 8];
            bf16x8 b3 = *(const bf16x8*)&Bt[48 + m][ks + q * 8];
            acc0 = __builtin_amdgcn_mfma_f32_16x16x32_bf16(af, b0, acc0, 0, 0, 0);
            acc1 = __builtin_amdgcn_mfma_f32_16x16x32_bf16(af, b1, acc1, 0, 0, 0);
            acc2 = __builtin_amdgcn_mfma_f32_16x16x32_bf16(af, b2, acc2, 0, 0, 0);
            acc3 = __builtin_amdgcn_mfma_f32_16x16x32_bf16(af, b3, acc3, 0, 0, 0);
        }

        #pragma unroll
        for (int reg = 0; reg < 4; reg++) {
            int grow = row0 + w * 16 + q * 4 + reg;
            if (grow < N_NODES) {
                support[(size_t)grow * NHID +  0 + m] = f2bf(acc0[reg]);
                support[(size_t)grow * NHID + 16 + m] = f2bf(acc1[reg]);
                support[(size_t)grow * NHID + 32 + m] = f2bf(acc2[reg]);
                support[(size_t)grow * NHID + 48 + m] = f2bf(acc3[reg]);
            }
        }
    } else {
        // ---------------- Bucket role: 2048 edges ----------------
        const int bblk = bid >> 1;                             // 0..781
        int2* stage = (int2*)smem;                             // 16 KB
        unsigned short* bkid = (unsigned short*)(smem + 16384); // 4 KB
        int* lcnt  = (int*)(smem + 20480);                     // 4 KB
        int* lexcl = (int*)(smem + 24576);                     // 4 KB
        int* lbase = (int*)(smem + 28672);                     // 4 KB
        int* p     = lbase;                                    // overlays lbase (2KB used)

        for (int b = t; b < 1024; b += 512) lcnt[b] = 0;
        __syncthreads();

        const int e0 = bblk * CHUNK;
        const int ctot = (e0 + CHUNK <= N_EDGES) ? CHUNK : (N_EDGES - e0);
        int bk[4];
        int val[4];
        float w[4];
        #pragma unroll
        for (int i = 0; i < 4; i++) {
            int e = e0 + i * 512 + t;
            if (e < N_EDGES) {
                int r = row[e];
                int c = col[e];
                w[i] = ew[e];
                bk[i] = r >> BSHIFT;
                val[i] = ((r & ((1 << BSHIFT) - 1)) << 17) | c;
                atomicAdd(&lcnt[bk[i]], 1);
            } else {
                bk[i] = -1;
            }
        }
        __syncthreads();

        // Block-level exclusive scan of 1024 bucket counts (2 per thread).
        int s0 = lcnt[t * 2 + 0], s1 = lcnt[t * 2 + 1];
        int tsum = s0 + s1;
        p[t] = tsum;
        __syncthreads();
        #pragma unroll
        for (int off = 1; off < 512; off <<= 1) {
            int u = (t >= off) ? p[t - off] : 0;
            __syncthreads();
            p[t] += u;
            __syncthreads();
        }
        int pe = p[t] - tsum;
        __syncthreads();   // p reads done before lbase overwrites
        lexcl[t * 2 + 0] = pe;
        lexcl[t * 2 + 1] = pe + s0;

        // Reserve slot runs; reset lcnt for ranking.
        for (int b = t; b < NBUCK; b += 512) {
            int c = lcnt[b];
            lbase[b] = c ? (b * SLOTSZ + atomicAdd(&bcnt[b], c)) : 0;
        }
        __syncthreads();
        for (int b = t; b < 1024; b += 512) lcnt[b] = 0;
        __syncthreads();

        // Rank into LDS stage ordered by bucket.
        #pragma unroll
        for (int i = 0; i < 4; i++) {
            if (bk[i] >= 0) {
                int r = atomicAdd(&lcnt[bk[i]], 1);
                int pos = lexcl[bk[i]] + r;
                stage[pos] = make_int2(val[i], __float_as_int(w[i]));
                bkid[pos] = (unsigned short)bk[i];
            }
        }
        __syncthreads();

        // Linear sweep; slot-overflow guard (drop past CAP; p ~ 1e-26).
        for (int i = t; i < ctot; i += 512) {
            int b = bkid[i];
            int dest = lbase[b] + (i - lexcl[b]);
            if (dest < b * SLOTSZ + CAP) bucketed[dest] = stage[i];
        }
    }
}

// ---------------------------------------------------------------------------
// PlaceGather: one block per bucket. Phase 1: hist slot records -> scan ->
// rank into LDS stage2 (counting sort; rank pass re-reads L2-warm slots).
// Phase 2: gather from stage2 (quad-split inner loop), write agg rows
// (exactly the region this bucket's slots occupied), fused BN partials.
// 512 threads = 8 waves x 16 nodes.
// ---------------------------------------------------------------------------
__global__ __launch_bounds__(512) void placegather_kernel(const int* __restrict__ bcnt,
                                                          const int2* __restrict__ bucketed,
                                                          const unsigned short* __restrict__ support,
                                                          float* __restrict__ agg,
                                                          float* __restrict__ sums) {
    __shared__ int2 stage2[CAP];       // 20 KB (sorted bucket records)
    __shared__ int hcnt[128];
    __shared__ int sv[128];
    __shared__ int hexcl[129];
    __shared__ float red[2][8][64];    // 4 KB
    const int t = threadIdx.x;
    const int lane = t & 63;
    const int wv = t >> 6;
    const int q = lane >> 4;       // edge quarter
    const int fl = lane & 15;      // feature slot: features [4fl, 4fl+4)
    const int b = blockIdx.x;
    int nrec = bcnt[b];
    if (nrec > CAP) nrec = CAP;    // consistent with bucket guard

    if (t < 128) hcnt[t] = 0;
    __syncthreads();

    // Phase 1a: histogram local rows (lr masked: garbage-slot defense).
    for (int i = t; i < nrec; i += 512) {
        int2 rec = bucketed[b * SLOTSZ + i];
        atomicAdd(&hcnt[(rec.x >> 17) & 127], 1);
    }
    __syncthreads();

    // Phase 1b: scan 128 counts -> exclusive offsets.
    int v0 = (t < 128) ? hcnt[t] : 0;
    if (t < 128) sv[t] = v0;
    __syncthreads();
    #pragma unroll
    for (int off = 1; off < 128; off <<= 1) {
        int u = (t < 128 && t >= off) ? sv[t - off] : 0;
        __syncthreads();
        if (t < 128) sv[t] += u;
        __syncthreads();
    }
    if (t < 128) {
        int excl = sv[t] - v0;
        hexcl[t] = excl;
        hcnt[t] = excl;            // running cursor
        if (t == 127) hexcl[128] = sv[127];
    }
    __syncthreads();

    // Phase 1c: rank-scatter into sorted LDS (re-read slots, L2-warm).
    for (int i = t; i < nrec; i += 512) {
        int2 rec = bucketed[b * SLOTSZ + i];
        int lr = (rec.x >> 17) & 127;
        int pos = atomicAdd(&hcnt[lr], 1);
        stage2[pos] = make_int2(rec.x & 0x1FFFF, rec.y);
    }
    __syncthreads();

    // Phase 2: gather. Wave wv handles local rows [wv*16, wv*16+16).
    float s0 = 0.f, s1 = 0.f, s2 = 0.f, s3 = 0.f;
    float z0 = 0.f, z1 = 0.f, z2 = 0.f, z3 = 0.f;

    for (int i = wv * 16; i < wv * 16 + 16; i++) {
        const int jb = hexcl[i];
        const int je = hexcl[i + 1];
        float a0 = 0.f, a1 = 0.f, a2 = 0.f, a3 = 0.f;

        for (int base = jb; base < je; base += 16) {
            int2  mm[4];
            float ww[4];
            uint2 vv[4];
            #pragma unroll
            for (int g = 0; g < 4; g++) {
                int idx = base + (g << 2) + q;
                int ci = (idx < je) ? idx : je - 1;   // je > jb in this loop
                mm[g] = stage2[ci];
                ww[g] = (idx < je) ? __uint_as_float(mm[g].y) : 0.0f;
            }
            #pragma unroll
            for (int g = 0; g < 4; g++) {
                vv[g] = *(const uint2*)(support + (((size_t)(unsigned)mm[g].x) << 6) + (fl << 2));
            }
            #pragma unroll
            for (int g = 0; g < 4; g++) {
                a0 = fmaf(ww[g], __uint_as_float(vv[g].x << 16), a0);
                a1 = fmaf(ww[g], __uint_as_float(vv[g].x & 0xFFFF0000u), a1);
                a2 = fmaf(ww[g], __uint_as_float(vv[g].y << 16), a2);
                a3 = fmaf(ww[g], __uint_as_float(vv[g].y & 0xFFFF0000u), a3);
            }
        }

        // Combine the 4 quarters.
        a0 += __shfl_xor(a0, 16); a0 += __shfl_xor(a0, 32);
        a1 += __shfl_xor(a1, 16); a1 += __shfl_xor(a1, 32);
        a2 += __shfl_xor(a2, 16); a2 += __shfl_xor(a2, 32);
        a3 += __shfl_xor(a3, 16); a3 += __shfl_xor(a3, 32);

        int r = (b << BSHIFT) + i;
        if (lane < 16 && r < N_NODES) {
            float4 o = make_float4(a0, a1, a2, a3);
            *(float4*)&agg[(size_t)r * NHID + (fl << 2)] = o;
            s0 += a0; s1 += a1; s2 += a2; s3 += a3;
            z0 = fmaf(a0, a0, z0); z1 = fmaf(a1, a1, z1);
            z2 = fmaf(a2, a2, z2); z3 = fmaf(a3, a3, z3);
        }
    }

    if (lane < 16) {
        red[0][wv][(fl << 2) + 0] = s0;
        red[0][wv][(fl << 2) + 1] = s1;
        red[0][wv][(fl << 2) + 2] = s2;
        red[0][wv][(fl << 2) + 3] = s3;
        red[1][wv][(fl << 2) + 0] = z0;
        red[1][wv][(fl << 2) + 1] = z1;
        red[1][wv][(fl << 2) + 2] = z2;
        red[1][wv][(fl << 2) + 3] = z3;
    }
    __syncthreads();
    if (t < 64) {
        float acc = 0.f;
        #pragma unroll
        for (int k = 0; k < 8; k++) acc += red[0][k][t];
        atomicAdd(&sums[t], acc);
    } else if (t < 128) {
        int f = t - 64;
        float acc = 0.f;
        #pragma unroll
        for (int k = 0; k < 8; k++) acc += red[1][k][f];
        atomicAdd(&sums[64 + f], acc);
    }
}

// ---------------------------------------------------------------------------
// Threefry-2x32, 20 rounds, key=(0,42). Hand-verified vs JAX test vector.
// ---------------------------------------------------------------------------
__device__ __forceinline__ uint32_t rotl32(uint32_t x, int d) {
    return (x << d) | (x >> (32 - d));
}

__device__ __forceinline__ uint32_t threefry_bits(uint32_t i) {
    const uint32_t k0 = 0u, k1 = 42u;
    const uint32_t k2 = k0 ^ k1 ^ 0x1BD11BDAu;
    uint32_t x0 = 0u, x1 = i;
    x0 += k0; x1 += k1;
    x0 += x1; x1 = rotl32(x1, 13) ^ x0;
    x0 += x1; x1 = rotl32(x1, 15) ^ x0;
    x0 += x1; x1 = rotl32(x1, 26) ^ x0;
    x0 += x1; x1 = rotl32(x1, 6)  ^ x0;
    x0 += k1; x1 += k2 + 1u;
    x0 += x1; x1 = rotl32(x1, 17) ^ x0;
    x0 += x1; x1 = rotl32(x1, 29) ^ x0;
    x0 += x1; x1 = rotl32(x1, 16) ^ x0;
    x0 += x1; x1 = rotl32(x1, 24) ^ x0;
    x0 += k2; x1 += k0 + 2u;
    x0 += x1; x1 = rotl32(x1, 13) ^ x0;
    x0 += x1; x1 = rotl32(x1, 15) ^ x0;
    x0 += x1; x1 = rotl32(x1, 26) ^ x0;
    x0 += x1; x1 = rotl32(x1, 6)  ^ x0;
    x0 += k0; x1 += k1 + 3u;
    x0 += x1; x1 = rotl32(x1, 17) ^ x0;
    x0 += x1; x1 = rotl32(x1, 29) ^ x0;
    x0 += x1; x1 = rotl32(x1, 16) ^ x0;
    x0 += x1; x1 = rotl32(x1, 24) ^ x0;
    x0 += k1; x1 += k2 + 4u;
    x0 += x1; x1 = rotl32(x1, 13) ^ x0;
    x0 += x1; x1 = rotl32(x1, 15) ^ x0;
    x0 += x1; x1 = rotl32(x1, 26) ^ x0;
    x0 += x1; x1 = rotl32(x1, 6)  ^ x0;
    x0 += k2; x1 += k0 + 5u;
    return x0 ^ x1;
}

// ---------------------------------------------------------------------------
// Apply: float4 per thread. BN affine + ReLU + dropout; finalize fused.
// ---------------------------------------------------------------------------
__global__ __launch_bounds__(256) void apply_kernel(const float* __restrict__ agg,
                                                    const float* __restrict__ sums,
                                                    const float* __restrict__ gamma,
                                                    const float* __restrict__ beta,
                                                    float* __restrict__ out) {
    const int i0 = (blockIdx.x * 256 + threadIdx.x) * 4;
    if (i0 >= N_ELEMS) return;
    const int f0 = i0 & 63;
    const float inv_n = 1.0f / (float)N_NODES;

    float4 a = *(const float4*)&agg[i0];
    float4 o;
    #pragma unroll
    for (int k = 0; k < 4; k++) {
        int f = f0 + k;
        float mean = sums[f] * inv_n;
        float var = sums[64 + f] * inv_n - mean * mean;
        float sc = gamma[f] * rsqrtf(var + 1e-5f);
        float sh = beta[f] - mean * sc;
        float av = (k == 0) ? a.x : (k == 1) ? a.y : (k == 2) ? a.z : a.w;
        float v = fmaxf(fmaf(av, sc, sh), 0.0f);
        uint32_t bits = threefry_bits((uint32_t)(i0 + k));
        float u = __uint_as_float((bits >> 9) | 0x3F800000u) - 1.0f;
        float r = (u < 0.7f) ? v * (1.0f / 0.7f) : 0.0f;
        if (k == 0) o.x = r; else if (k == 1) o.y = r; else if (k == 2) o.z = r; else o.w = r;
    }
    *(float4*)&out[i0] = o;
}

// ---------------------------------------------------------------------------
extern "C" void kernel_launch(void* const* d_in, const int* in_sizes, int n_in,
                              void* d_out, int out_size, void* d_ws, size_t ws_size,
                              hipStream_t stream) {
    const float* x     = (const float*)d_in[0];
    const int*   row   = (const int*)d_in[1];
    const int*   col   = (const int*)d_in[2];
    const float* ew    = (const float*)d_in[3];
    const float* W     = (const float*)d_in[4];
    const float* gamma = (const float*)d_in[6];
    const float* beta  = (const float*)d_in[7];
    float* out = (float*)d_out;

    float* sums       = (float*)d_ws;                      // 128 f32
    int*   bcnt       = (int*)(sums + 128);                // 1024 i32 (782 used)
    float* agg        = (float*)(bcnt + 1024);             // 25.62 MB (NBUCK*SLOTSZ*8)
    unsigned short* support = (unsigned short*)out;        // 6.4M bf16, in d_out
    int2*  bucketed   = (int2*)agg;                        // slotted, stride SLOTSZ

    // zero sums + bcnt (contiguous)
    hipMemsetAsync(d_ws, 0, (size_t)(128 + 1024) * 4, stream);

    gemm_bucket_kernel<<<GB_TOTAL, 512, GB_LDS, stream>>>(x, W, support,
                                                          row, col, ew, bcnt, bucketed);
    placegather_kernel<<<NBUCK, 512, 0, stream>>>(bcnt, bucketed, support, agg, sums);
    apply_kernel<<<(N_ELEMS / 4 + 255) / 256, 256, 0, stream>>>(agg, sums, gamma, beta, out);
}